// Round 2
// baseline (185.383 us; speedup 1.0000x reference)
//
#include <hip/hip_runtime.h>

#define HW 16384
#define LDS_W 72   // padded X-tile row stride (144 B): 16B-aligned rows, 2-way-free b128 reads

typedef __attribute__((ext_vector_type(8))) __bf16 bf16x8;
typedef __attribute__((ext_vector_type(4))) float floatx4;
typedef __attribute__((ext_vector_type(8))) unsigned short ushort8_t;

__device__ __forceinline__ unsigned short f2bf(float f) {
    // round-to-nearest-even fp32 -> bf16
    unsigned int u = __builtin_bit_cast(unsigned int, f);
    unsigned int r = (u + 0x7FFFu + ((u >> 16) & 1u)) >> 16;
    return (unsigned short)r;
}

__global__ void wconv_kernel(const float* __restrict__ w, unsigned short* __restrict__ wb) {
    int i = blockIdx.x * 256 + threadIdx.x;   // 65536 elements
    wb[i] = f2bf(w[i]);
}

// One block: 256 output channels x 64 pixels, K=256 in 4 steps.
// 8 waves: wave wv -> m-group (wv&3) (16 rows x 4 channel-groups), n-half (wv>>2) (2 of 4 pixel tiles).
// W fragments load directly from global bf16 (L1/L2-resident, 128 KB total).
// Lifting epilogue stays lane-local: lane's 4 group-accumulators are (a,b,c,d) at same (q,pixel).
__global__ __launch_bounds__(512, 4) void fused_gemm_lift(
        const float* __restrict__ x,
        const unsigned short* __restrict__ wb,
        const float* __restrict__ lp_v,
        const float* __restrict__ hp_v,
        const float* __restrict__ lp_h,
        const float* __restrict__ hp_h,
        float* __restrict__ out) {
    __shared__ unsigned short xs_s[64 * LDS_W];   // 9216 B: X^T tile [pixel][k] bf16

    const int tid   = threadIdx.x;
    const int wv    = tid >> 6;
    const int lane  = tid & 63;
    const int mgrp  = wv & 3;       // which 16-row slice of each 64-channel group
    const int nhalf = wv >> 2;      // which pair of pixel tiles
    const int tile  = blockIdx.x & 255;
    const int bb    = blockIdx.x >> 8;
    const int p0    = tile * 64;

    const float* xb = x + (size_t)bb * 256 * HW;

    const int lrow = lane & 15;
    const int lk8  = (lane >> 4) * 8;

    floatx4 acc[4][2];
    #pragma unroll
    for (int g = 0; g < 4; ++g)
        #pragma unroll
        for (int n = 0; n < 2; ++n) {
            floatx4 z = {0.f, 0.f, 0.f, 0.f};
            acc[g][n] = z;
        }

    const int sp  = tid & 63;    // staging pixel
    const int scg = tid >> 6;    // staging channel octet (8 channels per thread)

    for (int kt = 0; kt < 4; ++kt) {
        const int c0 = kt * 64;
        if (kt) __syncthreads();

        // ---- stage X tile transposed: global [c][p] fp32 -> LDS [p][c] bf16, one b128 write ----
        {
            const float* xsrc = xb + (size_t)(c0 + scg * 8) * HW + p0 + sp;
            ushort8_t v;
            #pragma unroll
            for (int j = 0; j < 8; ++j)
                v[j] = f2bf(xsrc[(size_t)j * HW]);
            *reinterpret_cast<ushort8_t*>(&xs_s[sp * LDS_W + scg * 8]) = v;
        }
        __syncthreads();

        // ---- MFMA: A-fragments from global wb (cache-hit), B-fragments from LDS ----
        #pragma unroll
        for (int kc = 0; kc < 2; ++kc) {
            bf16x8 af[4], bfr[2];
            #pragma unroll
            for (int g = 0; g < 4; ++g)
                af[g] = *reinterpret_cast<const bf16x8*>(
                    wb + (size_t)(g * 64 + mgrp * 16 + lrow) * 256 + c0 + kc * 32 + lk8);
            #pragma unroll
            for (int n = 0; n < 2; ++n)
                bfr[n] = *reinterpret_cast<const bf16x8*>(
                    &xs_s[((nhalf * 2 + n) * 16 + lrow) * LDS_W + kc * 32 + lk8]);
            #pragma unroll
            for (int g = 0; g < 4; ++g)
                #pragma unroll
                for (int n = 0; n < 2; ++n)
                    acc[g][n] = __builtin_amdgcn_mfma_f32_16x16x32_bf16(af[g], bfr[n], acc[g][n], 0, 0, 0);
        }
    }

    // ---- fused lifting epilogue (lane-local) ----
    // C/D map: col = lane&15 (pixel), row = 4*(lane>>4)+reg (channel)
    const int lgr = lane >> 4;
    #pragma unroll
    for (int ri = 0; ri < 4; ++ri) {
        const int q = mgrp * 16 + lgr * 4 + ri;     // 0..63
        const float lv0 = lp_v[2 * q], lv1 = lp_v[2 * q + 1];
        const float hv0 = hp_v[2 * q], hv1 = hp_v[2 * q + 1];
        const float lh0 = lp_h[2 * q], lh1 = lp_h[2 * q + 1];
        const float hh0 = hp_h[2 * q], hh1 = hp_h[2 * q + 1];
        float* outq = out + (size_t)(bb * 64 + q) * 65536;   // [256][256] plane
        #pragma unroll
        for (int n = 0; n < 2; ++n) {
            const int p = p0 + (nhalf * 2 + n) * 16 + lrow;
            const int h = p >> 7;
            const int w = p & 127;
            const float a  = acc[0][n][ri];
            const float b2 = acc[1][n][ri];
            const float c2 = acc[2][n][ri];
            const float d2 = acc[3][n][ri];
            const float xl0 = lv0 * a + lv1 * b2;
            const float xl1 = hv0 * a + hv1 * b2;
            const float xh0 = lv0 * c2 + lv1 * d2;
            const float xh1 = hv0 * c2 + hv1 * d2;
            float2 r0 = make_float2(lh0 * xl0 + lh1 * xh0, hh0 * xl0 + hh1 * xh0);
            float2 r1 = make_float2(lh0 * xl1 + lh1 * xh1, hh0 * xl1 + hh1 * xh1);
            *reinterpret_cast<float2*>(outq + (size_t)(2 * h) * 256 + 2 * w)     = r0;
            *reinterpret_cast<float2*>(outq + (size_t)(2 * h + 1) * 256 + 2 * w) = r1;
        }
    }
}

extern "C" void kernel_launch(void* const* d_in, const int* in_sizes, int n_in,
                              void* d_out, int out_size, void* d_ws, size_t ws_size,
                              hipStream_t stream) {
    const float* x   = (const float*)d_in[0];
    const float* w   = (const float*)d_in[1];
    const float* lpv = (const float*)d_in[2];
    const float* hpv = (const float*)d_in[3];
    const float* lph = (const float*)d_in[4];
    const float* hph = (const float*)d_in[5];
    float* outp = (float*)d_out;
    unsigned short* wb = (unsigned short*)d_ws;   // 128 KB bf16 weights

    wconv_kernel<<<dim3(256), dim3(256), 0, stream>>>(w, wb);
    fused_gemm_lift<<<dim3(4096), dim3(512), 0, stream>>>(x, wb, lpv, hpv, lph, hph, outp);
}

// Round 3
// 132.529 us; speedup vs baseline: 1.3988x; 1.3988x over previous
//
#include <hip/hip_runtime.h>

#define HW 16384

typedef __attribute__((ext_vector_type(8))) __bf16 bf16x8;
typedef __attribute__((ext_vector_type(4))) float floatx4;
typedef __attribute__((ext_vector_type(8))) unsigned short ushort8_t;

typedef const __attribute__((address_space(1))) unsigned int gu32;
typedef __attribute__((address_space(3))) unsigned int lu32;

__device__ __forceinline__ unsigned short f2bf(float f) {
    // round-to-nearest-even fp32 -> bf16
    unsigned int u = __builtin_bit_cast(unsigned int, f);
    unsigned int r = (u + 0x7FFFu + ((u >> 16) & 1u)) >> 16;
    return (unsigned short)r;
}

__device__ __forceinline__ void gload_lds16(const unsigned short* g, unsigned short* l) {
    __builtin_amdgcn_global_load_lds((gu32*)g, (lu32*)l, 16, 0, 0);
}

// Pre-convert W to bf16 in per-kt tiles [256 rows][64 k], XOR-swizzled so the main
// kernel can global_load_lds linearly and ds_read with the same involution.
// ushort index within tile: (row*64 + kl) ^ ((row&7)<<3); tile kt base = kt*16384.
__global__ void wconv_kernel(const float* __restrict__ w, unsigned short* __restrict__ wb) {
    int i = blockIdx.x * 256 + threadIdx.x;   // 65536 elements, i = row*256 + c
    int row = i >> 8, c = i & 255;
    int kt = c >> 6, kl = c & 63;
    int idx = (row * 64 + kl) ^ ((row & 7) << 3);
    wb[kt * 16384 + idx] = f2bf(w[i]);
}

// Block: 256 output channels x 128 pixels, K=256 in 4 steps of 64.
// 8 waves: mgrp = wv&3 (16-row slice per 64-ch group), nhalf = wv>>2 (64-px half).
// W double-buffered via global_load_lds (pre-swizzled); X transposed+converted via
// register prefetch, single-buffered. Loads for kt+1 issue before kt's MFMA phase.
// Lifting epilogue lane-local: lane's 4 group-accumulators = (a,b,c,d) at same (q,pixel).
__global__ __launch_bounds__(512, 4) void fused_gemm_lift(
        const float* __restrict__ x,
        const unsigned short* __restrict__ wb,
        const float* __restrict__ lp_v,
        const float* __restrict__ hp_v,
        const float* __restrict__ lp_h,
        const float* __restrict__ hp_h,
        float* __restrict__ out) {
    __shared__ alignas(16) unsigned short wbuf_s[2][16384];  // 2 x 32 KB W tiles
    __shared__ alignas(16) unsigned short xbuf_s[8192];      // 16 KB X^T tile [128 px][64 k]

    const int tid  = threadIdx.x;
    const int wv   = tid >> 6;
    const int lane = tid & 63;
    const int mgrp  = wv & 3;
    const int nhalf = wv >> 2;
    const int tile = blockIdx.x & 127;
    const int bb   = blockIdx.x >> 7;
    const int p0   = tile * 128;

    const float* xb = x + (size_t)bb * 256 * HW;

    const int lrow  = lane & 15;
    const int khalf = lane >> 4;              // 0..3: which 8-elem k chunk
    const int fswz  = (lrow & 7) << 3;        // frag-read XOR (ushort units)

    // staging thread mapping: pixel px, 16 consecutive channels starting at cb
    const int px  = tid & 127;
    const int cb  = (tid >> 7) * 16;
    const int xw0 = (px * 64 + cb) ^ ((px & 7) << 3);
    const int xw1 = (px * 64 + cb + 8) ^ ((px & 7) << 3);

    floatx4 acc[4][4];
    #pragma unroll
    for (int g = 0; g < 4; ++g)
        #pragma unroll
        for (int n = 0; n < 4; ++n) {
            floatx4 z = {0.f, 0.f, 0.f, 0.f};
            acc[g][n] = z;
        }

    float xv[16];

    // ---- prologue: X[0] -> regs, W[0] -> wbuf[0] ----
    {
        const float* xs = xb + (size_t)cb * HW + p0 + px;
        #pragma unroll
        for (int j = 0; j < 16; ++j) xv[j] = xs[(size_t)j * HW];
        #pragma unroll
        for (int pass = 0; pass < 4; ++pass) {
            int ch = pass * 512 + wv * 64;   // wave-uniform chunk base
            gload_lds16(wb + (size_t)(ch + lane) * 8, &wbuf_s[0][ch * 8]);
        }
        ushort8_t v0, v1;
        #pragma unroll
        for (int j = 0; j < 8; ++j) { v0[j] = f2bf(xv[j]); v1[j] = f2bf(xv[8 + j]); }
        *reinterpret_cast<ushort8_t*>(&xbuf_s[xw0]) = v0;
        *reinterpret_cast<ushort8_t*>(&xbuf_s[xw1]) = v1;
    }
    __syncthreads();   // drains vmcnt+lgkm: wbuf[0], xbuf ready

    for (int kt = 0; kt < 4; ++kt) {
        const int cw = kt & 1;

        // ---- issue next-tile loads BEFORE compute (latency hidden under MFMA) ----
        if (kt < 3) {
            const float* xs = xb + (size_t)((kt + 1) * 64 + cb) * HW + p0 + px;
            #pragma unroll
            for (int j = 0; j < 16; ++j) xv[j] = xs[(size_t)j * HW];
            #pragma unroll
            for (int pass = 0; pass < 4; ++pass) {
                int ch = pass * 512 + wv * 64;
                gload_lds16(wb + (size_t)((kt + 1) * 16384) + (size_t)(ch + lane) * 8,
                            &wbuf_s[cw ^ 1][ch * 8]);
            }
        }

        // ---- MFMA phase ----
        #pragma unroll
        for (int kc = 0; kc < 2; ++kc) {
            bf16x8 af[4], bfr[4];
            #pragma unroll
            for (int g = 0; g < 4; ++g)
                af[g] = *reinterpret_cast<const bf16x8*>(
                    &wbuf_s[cw][((g * 64 + mgrp * 16 + lrow) * 64 + kc * 32 + khalf * 8) ^ fswz]);
            #pragma unroll
            for (int n = 0; n < 4; ++n)
                bfr[n] = *reinterpret_cast<const bf16x8*>(
                    &xbuf_s[((nhalf * 64 + n * 16 + lrow) * 64 + kc * 32 + khalf * 8) ^ fswz]);
            #pragma unroll
            for (int g = 0; g < 4; ++g)
                #pragma unroll
                for (int n = 0; n < 4; ++n)
                    acc[g][n] = __builtin_amdgcn_mfma_f32_16x16x32_bf16(af[g], bfr[n], acc[g][n], 0, 0, 0);
        }

        // ---- commit X[kt+1] into xbuf (single-buffered: barrier both sides) ----
        if (kt < 3) {
            __syncthreads();   // all waves done reading xbuf; in-flight loads have landed under MFMA
            ushort8_t v0, v1;
            #pragma unroll
            for (int j = 0; j < 8; ++j) { v0[j] = f2bf(xv[j]); v1[j] = f2bf(xv[8 + j]); }
            *reinterpret_cast<ushort8_t*>(&xbuf_s[xw0]) = v0;
            *reinterpret_cast<ushort8_t*>(&xbuf_s[xw1]) = v1;
            __syncthreads();
        }
    }

    // ---- fused lifting epilogue (lane-local) ----
    // C/D map: col = lane&15 (pixel), row = 4*(lane>>4)+reg (channel)
    const int lgr = lane >> 4;
    #pragma unroll
    for (int ri = 0; ri < 4; ++ri) {
        const int q = mgrp * 16 + lgr * 4 + ri;     // 0..63
        const float lv0 = lp_v[2 * q], lv1 = lp_v[2 * q + 1];
        const float hv0 = hp_v[2 * q], hv1 = hp_v[2 * q + 1];
        const float lh0 = lp_h[2 * q], lh1 = lp_h[2 * q + 1];
        const float hh0 = hp_h[2 * q], hh1 = hp_h[2 * q + 1];
        float* outq = out + (size_t)(bb * 64 + q) * 65536;   // [256][256] plane
        #pragma unroll
        for (int n = 0; n < 4; ++n) {
            const int p = p0 + nhalf * 64 + n * 16 + lrow;
            const int h = p >> 7;
            const int w = p & 127;
            const float a  = acc[0][n][ri];
            const float b2 = acc[1][n][ri];
            const float c2 = acc[2][n][ri];
            const float d2 = acc[3][n][ri];
            const float xl0 = lv0 * a + lv1 * b2;
            const float xl1 = hv0 * a + hv1 * b2;
            const float xh0 = lv0 * c2 + lv1 * d2;
            const float xh1 = hv0 * c2 + hv1 * d2;
            float2 r0 = make_float2(lh0 * xl0 + lh1 * xh0, hh0 * xl0 + hh1 * xh0);
            float2 r1 = make_float2(lh0 * xl1 + lh1 * xh1, hh0 * xl1 + hh1 * xh1);
            *reinterpret_cast<float2*>(outq + (size_t)(2 * h) * 256 + 2 * w)     = r0;
            *reinterpret_cast<float2*>(outq + (size_t)(2 * h + 1) * 256 + 2 * w) = r1;
        }
    }
}

extern "C" void kernel_launch(void* const* d_in, const int* in_sizes, int n_in,
                              void* d_out, int out_size, void* d_ws, size_t ws_size,
                              hipStream_t stream) {
    const float* x   = (const float*)d_in[0];
    const float* w   = (const float*)d_in[1];
    const float* lpv = (const float*)d_in[2];
    const float* hpv = (const float*)d_in[3];
    const float* lph = (const float*)d_in[4];
    const float* hph = (const float*)d_in[5];
    float* outp = (float*)d_out;
    unsigned short* wbp = (unsigned short*)d_ws;   // 128 KB bf16 weights, pre-swizzled tiles

    wconv_kernel<<<dim3(256), dim3(256), 0, stream>>>(w, wbp);
    fused_gemm_lift<<<dim3(2048), dim3(512), 0, stream>>>(x, wbp, lpv, hpv, lph, hph, outp);
}